// Round 7
// baseline (145.203 us; speedup 1.0000x reference)
//
#include <hip/hip_runtime.h>
#include <cstdint>
#include <cstddef>

// Problem constants
#define FF 64
#define EE 64
#define HH 8
#define PP 512
#define MM 16384   // B*T = 64*256
#define KK 1024    // 2 * F * H  (both branches concatenated)

typedef __bf16 bf16x8 __attribute__((ext_vector_type(8)));
typedef float  floatx4 __attribute__((ext_vector_type(4)));

// float -> bf16 (RNE)
__device__ __forceinline__ unsigned short f2bf(float f) {
    unsigned int u = __float_as_uint(f);
    u += 0x7FFFu + ((u >> 16) & 1u);
    return (unsigned short)(u >> 16);
}

__device__ __forceinline__ unsigned pack2(unsigned short a, unsigned short b) {
    return (unsigned)a | ((unsigned)b << 16);
}

// tanh from pre-scaled arg t = (val*w+b)*2*log2e:  1 - 2/(exp2(t)+1)
__device__ __forceinline__ float fast_tanh_s(float t) {
    float e, r;
    asm("v_exp_f32 %0, %1" : "=v"(e) : "v"(t));
    float d = e + 1.0f;
    asm("v_rcp_f32 %0, %1" : "=v"(r) : "v"(d));
    return __builtin_fmaf(-2.0f, r, 1.0f);
}

// ---------------------------------------------------------------------------
// Phase 1: BmatT[n][k] (bf16, k-contiguous), k = br*512 + f*8 + h
//   BmatT[n][br,f,h] = sum_e w2[f,h,e] * W[(f*64+e)*512 + n]
// ---------------------------------------------------------------------------
__global__ __launch_bounds__(256) void combine_kernel(
    const float* __restrict__ w2v, const float* __restrict__ w2t,
    const float* __restrict__ wx,  const float* __restrict__ wt,
    unsigned short* __restrict__ BmatT)
{
    const int tid = threadIdx.x;
    const int bid = blockIdx.x;
    const int br = bid >> 7;
    const int f  = (bid >> 1) & 63;
    const int nh = bid & 1;
    const float* __restrict__ w2 = br ? w2t : w2v;   // [F][H][E]
    const float* __restrict__ W  = br ? wt  : wx;    // [F*E][P]
    __shared__ float w2s[HH * EE];
    for (int i = tid; i < HH * EE; i += 256) w2s[i] = w2[f * HH * EE + i];
    __syncthreads();
    const int n = nh * 256 + tid;
    float acc[HH] = {0,0,0,0,0,0,0,0};
    const float* Wcol = W + (size_t)f * EE * PP + n;
    #pragma unroll 8
    for (int e = 0; e < EE; ++e) {
        const float wv = Wcol[(size_t)e * PP];
        #pragma unroll
        for (int h = 0; h < HH; ++h)
            acc[h] = __builtin_fmaf(w2s[h * EE + e], wv, acc[h]);
    }
    uint4 v;
    v.x = pack2(f2bf(acc[0]), f2bf(acc[1]));
    v.y = pack2(f2bf(acc[2]), f2bf(acc[3]));
    v.z = pack2(f2bf(acc[4]), f2bf(acc[5]));
    v.w = pack2(f2bf(acc[6]), f2bf(acc[7]));
    *reinterpret_cast<uint4*>(&BmatT[(size_t)n * KK + br * 512 + f * 8]) = v;
}

// ---------------------------------------------------------------------------
// Phase 2: fused featurize + GEMM — B DIRECT FROM GLOBAL (L2-resident).
//   out[m][n] = sum_k A[m][k]*BmatT[n][k] + bx[n] + bt[n]
//   A[m][br*512+f*8+h] = tanh(in_br[m][f]*w1[f][h]+b1[f][h])  in-tile.
// 256 threads / 4 waves, each wave a 64x64 tile (4x4 acc of 16x16x32).
// Block tile 64m x 256n, BK=64, grid (256,2) -> 2 blocks/CU.
// B-fragments are 16 contiguous bytes of Bt[n][k] -> per-lane
// global_load_dwordx4 (Bt = 1 MB, L2-resident). This removes B's 268 MB LDS
// write + 268 MB LDS read (LDS now A-only: ~335 MB) and makes barrier 1
// lgkm-only; B loads pipeline freely across the MFMA phase with no barrier
// interaction (the r1..r6 DMA-staging drain is gone).
// Per-iter: input prefetch ISSUED FIRST, then B loads (in-order vmcnt: the
// tanh's wait doesn't drain the B queue).
// As XOR-swizzle: row r's logical 16B chunk c at physical c^(r&7).
// ---------------------------------------------------------------------------
__global__ __launch_bounds__(256, 2) void gemm_fused_kernel(
    const float* __restrict__ x,   const float* __restrict__ tmv,
    const float* __restrict__ w1v, const float* __restrict__ b1v,
    const float* __restrict__ w1t, const float* __restrict__ b1t,
    const unsigned short* __restrict__ Bt,  // BmatT [PP][KK]
    const float* __restrict__ bx, const float* __restrict__ bt,
    float* __restrict__ out)                 // [MM][PP]
{
    __shared__ __align__(16) unsigned short As[64 * 64];    // 8 KB
    __shared__ __align__(16) float w1s[2 * FF * HH];        // 4 KB (pre-scaled)
    __shared__ __align__(16) float b1s[2 * FF * HH];        // 4 KB (pre-scaled)

    const int tid  = threadIdx.x;
    const int wave = tid >> 6;
    const int lane = tid & 63;
    const int m0 = blockIdx.x * 64;
    const int n0 = blockIdx.y * 256;

    // stage w1/b1 scaled by 2*log2e
    {
        const float c = 2.8853900817779268f;
        const float4 wsrc = (tid < 128) ? reinterpret_cast<const float4*>(w1v)[tid]
                                        : reinterpret_cast<const float4*>(w1t)[tid - 128];
        const float4 bsrc = (tid < 128) ? reinterpret_cast<const float4*>(b1v)[tid]
                                        : reinterpret_cast<const float4*>(b1t)[tid - 128];
        float4 ws, bs;
        ws.x = wsrc.x * c; ws.y = wsrc.y * c; ws.z = wsrc.z * c; ws.w = wsrc.w * c;
        bs.x = bsrc.x * c; bs.y = bsrc.y * c; bs.z = bsrc.z * c; bs.w = bsrc.w * c;
        reinterpret_cast<float4*>(w1s)[tid] = ws;
        reinterpret_cast<float4*>(b1s)[tid] = bs;
    }

    const int wn  = wave;                  // 0..3: n quadrant (64 cols each)
    const int q   = lane >> 4;
    const int ml  = lane & 15;
    const int mlx = ml & 7;
    const int fi  = tid & 7;               // feature sub-index for A-compute
    const int g   = tid >> 3;              // 0..31: A rows g and g+32
    const int pchunkA = (fi ^ (g & 7)) * 8;

    // B base pointer for this lane: row n0+wn*64+ml (+nt*16), k offset q*8
    const unsigned short* BtL = Bt + (size_t)(n0 + wn * 64 + ml) * KK + q * 8;

    __syncthreads();   // w1s/b1s ready

    float4 wlo, whi, blo, bhi;
    float  va, vb;
    uint4  pa, pb;

    // prologue: it=0 (br=0, f=fi)
    wlo = reinterpret_cast<const float4*>(w1s)[fi * 2];
    whi = reinterpret_cast<const float4*>(w1s)[fi * 2 + 1];
    blo = reinterpret_cast<const float4*>(b1s)[fi * 2];
    bhi = reinterpret_cast<const float4*>(b1s)[fi * 2 + 1];
    va = x[(size_t)(m0 + g) * FF + fi];
    vb = x[(size_t)(m0 + g + 32) * FF + fi];

    auto tanh_pack = [&](float val) -> uint4 {
        float hv[8];
        hv[0] = fast_tanh_s(__builtin_fmaf(val, wlo.x, blo.x));
        hv[1] = fast_tanh_s(__builtin_fmaf(val, wlo.y, blo.y));
        hv[2] = fast_tanh_s(__builtin_fmaf(val, wlo.z, blo.z));
        hv[3] = fast_tanh_s(__builtin_fmaf(val, wlo.w, blo.w));
        hv[4] = fast_tanh_s(__builtin_fmaf(val, whi.x, bhi.x));
        hv[5] = fast_tanh_s(__builtin_fmaf(val, whi.y, bhi.y));
        hv[6] = fast_tanh_s(__builtin_fmaf(val, whi.z, bhi.z));
        hv[7] = fast_tanh_s(__builtin_fmaf(val, whi.w, bhi.w));
        uint4 v;
        v.x = pack2(f2bf(hv[0]), f2bf(hv[1]));
        v.y = pack2(f2bf(hv[2]), f2bf(hv[3]));
        v.z = pack2(f2bf(hv[4]), f2bf(hv[5]));
        v.w = pack2(f2bf(hv[6]), f2bf(hv[7]));
        return v;
    };
    pa = tanh_pack(va);
    pb = tanh_pack(vb);

    floatx4 acc[4][4];
    #pragma unroll
    for (int i = 0; i < 4; ++i)
        #pragma unroll
        for (int j = 0; j < 4; ++j)
            acc[i][j] = (floatx4){0.f, 0.f, 0.f, 0.f};

    for (int it = 0; it < 16; ++it) {
        const int k0 = it * 64;

        // ---- staging: two As stores (lgkm only — cheap barrier) ----
        *reinterpret_cast<uint4*>(&As[g * 64 + pchunkA])        = pa;
        *reinterpret_cast<uint4*>(&As[(g + 32) * 64 + pchunkA]) = pb;
        __syncthreads();

        // ---- prefetch it+1's inputs FIRST (so later vmcnt waits for
        //      them don't drain the B-load queue), then weights (LDS) ----
        const int itn = (it < 15) ? it + 1 : 15;
        const int brn = itn >> 3;
        const int fn  = ((itn & 7) << 3) + fi;
        const float* __restrict__ inpn = brn ? tmv : x;
        const float nva = inpn[(size_t)(m0 + g) * FF + fn];
        const float nvb = inpn[(size_t)(m0 + g + 32) * FF + fn];
        const float4 nwlo = reinterpret_cast<const float4*>(w1s)[brn * 128 + fn * 2];
        const float4 nwhi = reinterpret_cast<const float4*>(w1s)[brn * 128 + fn * 2 + 1];
        const float4 nblo = reinterpret_cast<const float4*>(b1s)[brn * 128 + fn * 2];
        const float4 nbhi = reinterpret_cast<const float4*>(b1s)[brn * 128 + fn * 2 + 1];

        // ---- issue all 8 B-fragment global loads (L2-resident Bt) ----
        bf16x8 bfr0[4], bfr1[4];
        #pragma unroll
        for (int nt = 0; nt < 4; ++nt)
            bfr0[nt] = *reinterpret_cast<const bf16x8*>(&BtL[(size_t)nt * 16 * KK + k0]);
        #pragma unroll
        for (int nt = 0; nt < 4; ++nt)
            bfr1[nt] = *reinterpret_cast<const bf16x8*>(&BtL[(size_t)nt * 16 * KK + k0 + 32]);

        // ---- MFMA phase ----
        {
            const int co0 = ((0 + q) ^ mlx) * 8;
            bf16x8 af[4];
            #pragma unroll
            for (int mt = 0; mt < 4; ++mt)
                af[mt] = *reinterpret_cast<const bf16x8*>(&As[(mt * 16 + ml) * 64 + co0]);
            #pragma unroll
            for (int mt = 0; mt < 4; ++mt)
                #pragma unroll
                for (int nt = 0; nt < 4; ++nt)
                    acc[mt][nt] = __builtin_amdgcn_mfma_f32_16x16x32_bf16(
                        af[mt], bfr0[nt], acc[mt][nt], 0, 0, 0);

            // next-iter tanh: pure VALU, overlaps MFMA issue
            wlo = nwlo; whi = nwhi; blo = nblo; bhi = nbhi;
            va = nva; vb = nvb;
            pa = tanh_pack(va);
            pb = tanh_pack(vb);

            const int co1 = ((4 + q) ^ mlx) * 8;
            #pragma unroll
            for (int mt = 0; mt < 4; ++mt)
                af[mt] = *reinterpret_cast<const bf16x8*>(&As[(mt * 16 + ml) * 64 + co1]);
            #pragma unroll
            for (int mt = 0; mt < 4; ++mt)
                #pragma unroll
                for (int nt = 0; nt < 4; ++nt)
                    acc[mt][nt] = __builtin_amdgcn_mfma_f32_16x16x32_bf16(
                        af[mt], bfr1[nt], acc[mt][nt], 0, 0, 0);
        }
        __syncthreads();   // all waves done reading As before overwrite
    }

    // epilogue: nt innermost -> 4 consecutive 64B chunks per output row
    float bias[4];
    #pragma unroll
    for (int nt = 0; nt < 4; ++nt) {
        const int n = n0 + wn * 64 + nt * 16 + ml;
        bias[nt] = bx[n] + bt[n];
    }
    #pragma unroll
    for (int mt = 0; mt < 4; ++mt) {
        const int mb = m0 + mt * 16 + q * 4;
        #pragma unroll
        for (int r = 0; r < 4; ++r) {
            float* orow = out + (size_t)(mb + r) * PP + n0 + wn * 64 + ml;
            #pragma unroll
            for (int nt = 0; nt < 4; ++nt)
                orow[nt * 16] = acc[mt][nt][r] + bias[nt];
        }
    }
}

// ---------------------------------------------------------------------------
extern "C" void kernel_launch(void* const* d_in, const int* in_sizes, int n_in,
                              void* d_out, int out_size, void* d_ws, size_t ws_size,
                              hipStream_t stream)
{
    const float* x   = (const float*)d_in[0];
    const float* tmv = (const float*)d_in[1];
    const float* w1v = (const float*)d_in[2];
    const float* b1v = (const float*)d_in[3];
    const float* w2v = (const float*)d_in[4];
    const float* w1t = (const float*)d_in[5];
    const float* b1t = (const float*)d_in[6];
    const float* w2t = (const float*)d_in[7];
    const float* wx  = (const float*)d_in[8];
    const float* bx  = (const float*)d_in[9];
    const float* wt  = (const float*)d_in[10];
    const float* bt  = (const float*)d_in[11];
    float* out = (float*)d_out;

    // ws: [0,1MB) BmatT bf16 [512][1024]
    unsigned short* Bws = (unsigned short*)d_ws;

    combine_kernel<<<256, 256, 0, stream>>>(w2v, w2t, wx, wt, Bws);
    gemm_fused_kernel<<<dim3(MM / 64, PP / 256), 256, 0, stream>>>(
        x, tmv, w1v, b1v, w1t, b1t, Bws, bx, bt, out);
}

// Round 8
// 129.458 us; speedup vs baseline: 1.1216x; 1.1216x over previous
//
#include <hip/hip_runtime.h>
#include <cstdint>
#include <cstddef>

// Problem constants
#define FF 64
#define EE 64
#define HH 8
#define PP 512
#define MM 16384   // B*T = 64*256
#define KK 1024    // 2 * F * H  (both branches concatenated)

typedef __bf16 bf16x8 __attribute__((ext_vector_type(8)));
typedef float  floatx4 __attribute__((ext_vector_type(4)));

// float -> bf16 (RNE)
__device__ __forceinline__ unsigned short f2bf(float f) {
    unsigned int u = __float_as_uint(f);
    u += 0x7FFFu + ((u >> 16) & 1u);
    return (unsigned short)(u >> 16);
}

__device__ __forceinline__ unsigned pack2(unsigned short a, unsigned short b) {
    return (unsigned)a | ((unsigned)b << 16);
}

// tanh from pre-scaled arg t = (val*w+b)*2*log2e:  1 - 2/(exp2(t)+1)
__device__ __forceinline__ float fast_tanh_s(float t) {
    float e, r;
    asm("v_exp_f32 %0, %1" : "=v"(e) : "v"(t));
    float d = e + 1.0f;
    asm("v_rcp_f32 %0, %1" : "=v"(r) : "v"(d));
    return __builtin_fmaf(-2.0f, r, 1.0f);
}

// async global->LDS, 16B per lane; dest = wave-uniform base + lane*16
__device__ __forceinline__ void gl_lds16(const unsigned short* g, unsigned short* s) {
    __builtin_amdgcn_global_load_lds(
        (__attribute__((address_space(1))) void*)(void*)g,
        (__attribute__((address_space(3))) void*)s,
        16, 0, 0);
}

// ---------------------------------------------------------------------------
// Phase 1: BmatT[n][k] (bf16, k-contiguous), k = br*512 + f*8 + h
//   BmatT[n][br,f,h] = sum_e w2[f,h,e] * W[(f*64+e)*512 + n]
// ---------------------------------------------------------------------------
__global__ __launch_bounds__(256) void combine_kernel(
    const float* __restrict__ w2v, const float* __restrict__ w2t,
    const float* __restrict__ wx,  const float* __restrict__ wt,
    unsigned short* __restrict__ BmatT)
{
    const int tid = threadIdx.x;
    const int bid = blockIdx.x;
    const int br = bid >> 7;
    const int f  = (bid >> 1) & 63;
    const int nh = bid & 1;
    const float* __restrict__ w2 = br ? w2t : w2v;   // [F][H][E]
    const float* __restrict__ W  = br ? wt  : wx;    // [F*E][P]
    __shared__ float w2s[HH * EE];
    for (int i = tid; i < HH * EE; i += 256) w2s[i] = w2[f * HH * EE + i];
    __syncthreads();
    const int n = nh * 256 + tid;
    float acc[HH] = {0,0,0,0,0,0,0,0};
    const float* Wcol = W + (size_t)f * EE * PP + n;
    #pragma unroll 8
    for (int e = 0; e < EE; ++e) {
        const float wv = Wcol[(size_t)e * PP];
        #pragma unroll
        for (int h = 0; h < HH; ++h)
            acc[h] = __builtin_fmaf(w2s[h * EE + e], wv, acc[h]);
    }
    uint4 v;
    v.x = pack2(f2bf(acc[0]), f2bf(acc[1]));
    v.y = pack2(f2bf(acc[2]), f2bf(acc[3]));
    v.z = pack2(f2bf(acc[4]), f2bf(acc[5]));
    v.w = pack2(f2bf(acc[6]), f2bf(acc[7]));
    *reinterpret_cast<uint4*>(&BmatT[(size_t)n * KK + br * 512 + f * 8]) = v;
}

// ---------------------------------------------------------------------------
// Phase 2: fused featurize + GEMM with DOUBLE-BUFFERED B-DMA and manual
// partial-drain barriers (hipBLASLt-style: prefetch stays in flight across
// the barrier; __syncthreads() would emit vmcnt(0) and kill it).
//   out[m][n] = sum_k A[m][k]*BmatT[n][k] + bx[n] + bt[n]
//   A[m][br*512+f*8+h] = tanh(in_br[m][f]*w1[f][h]+b1[f][h])  in-tile.
// 256 threads / 4 waves, wave tile 64m x 64n (4x4 of 16x16x32 MFMA).
// Block tile 64m x 256n, BK=32, 32 iters, grid (256,2) -> 2 blocks/CU.
// Per iter, issue order (vmcnt is in-order!):
//   [1 input load (it+1)] [4 B-DMA (it+1) -> buf^1] [As store (it)]
//   [w/b LDS reads (it+1)]
//   barrier1 = s_waitcnt vmcnt(5) lgkmcnt(0); s_barrier
//       -> waits DMA(it) (6th-oldest), leaves it+1's 5 vmem in flight
//   MFMA(it) from Bs[buf] + As; tanh(it+1) pure-VALU (compiler waits
//       vmcnt(4) for the input — DMA(it+1) stays outstanding)
//   barrier2 = s_waitcnt lgkmcnt(0); s_barrier   (no vmcnt drain at all)
// LDS 44 KB static: Bs 2x16K + As 4K + w1s/b1s 8K.
// Swizzle (BK=32: 4 chunks/row): logical chunk c of row r at physical
// (c+(r>>1))&3 -> frag ds_read_b128 lands 2 lanes/bank (free, m136).
// ---------------------------------------------------------------------------
__global__ __launch_bounds__(256, 2) void gemm_fused_kernel(
    const float* __restrict__ x,   const float* __restrict__ tmv,
    const float* __restrict__ w1v, const float* __restrict__ b1v,
    const float* __restrict__ w1t, const float* __restrict__ b1t,
    const unsigned short* __restrict__ Bt,  // BmatT [PP][KK]
    const float* __restrict__ bx, const float* __restrict__ bt,
    float* __restrict__ out)                 // [MM][PP]
{
    __shared__ __align__(16) unsigned short Bs[2 * 256 * 32]; // 32 KB (dbuf)
    __shared__ __align__(16) unsigned short As[64 * 32];      // 4 KB
    __shared__ __align__(16) float w1s[2 * FF * HH];          // 4 KB (pre-scaled)
    __shared__ __align__(16) float b1s[2 * FF * HH];          // 4 KB (pre-scaled)

    const int tid  = threadIdx.x;
    const int wave = tid >> 6;
    const int lane = tid & 63;
    const int m0 = blockIdx.x * 64;
    const int n0 = blockIdx.y * 256;

    // stage w1/b1 scaled by 2*log2e
    {
        const float c = 2.8853900817779268f;
        const float4 wsrc = (tid < 128) ? reinterpret_cast<const float4*>(w1v)[tid]
                                        : reinterpret_cast<const float4*>(w1t)[tid - 128];
        const float4 bsrc = (tid < 128) ? reinterpret_cast<const float4*>(b1v)[tid]
                                        : reinterpret_cast<const float4*>(b1t)[tid - 128];
        float4 ws, bs;
        ws.x = wsrc.x * c; ws.y = wsrc.y * c; ws.z = wsrc.z * c; ws.w = wsrc.w * c;
        bs.x = bsrc.x * c; bs.y = bsrc.y * c; bs.z = bsrc.z * c; bs.w = bsrc.w * c;
        reinterpret_cast<float4*>(w1s)[tid] = ws;
        reinterpret_cast<float4*>(b1s)[tid] = bs;
    }

    const int wn  = wave;                  // 0..3: n quadrant (64 cols)
    const int q   = lane >> 4;             // 0..3: k-chunk of the frag
    const int ml  = lane & 15;
    // frag LDS chunk offset (shorts): physical chunk (q+(ml>>1))&3
    const int fco = ((q + (ml >> 1)) & 3) * 8;
    // A producer: thread (fi2 = tid&3, arow = tid>>2)
    const int fi2  = tid & 3;
    const int arow = tid >> 2;             // 0..63
    const int asoff = arow * 32 + ((fi2 + (arow >> 1)) & 3) * 8;
    // B-DMA per-lane global mapping: lds slot lane*16 -> row seg*16+(lane>>2),
    // physical chunk lane&3 -> logical chunk ((lane&3)-((lane>>3)&3))&3
    const int laneClog = ((lane & 3) - ((lane >> 3) & 3)) & 3;
    const unsigned short* BtLane =
        Bt + (size_t)(n0 + (lane >> 2)) * KK + laneClog * 8;

    __syncthreads();   // w1s/b1s ready (clean vmcnt slate)

    float4 wlo, whi, blo, bhi;
    uint4  pa;

    auto tanh_pack = [&](float val) -> uint4 {
        float hv[8];
        hv[0] = fast_tanh_s(__builtin_fmaf(val, wlo.x, blo.x));
        hv[1] = fast_tanh_s(__builtin_fmaf(val, wlo.y, blo.y));
        hv[2] = fast_tanh_s(__builtin_fmaf(val, wlo.z, blo.z));
        hv[3] = fast_tanh_s(__builtin_fmaf(val, wlo.w, blo.w));
        hv[4] = fast_tanh_s(__builtin_fmaf(val, whi.x, bhi.x));
        hv[5] = fast_tanh_s(__builtin_fmaf(val, whi.y, bhi.y));
        hv[6] = fast_tanh_s(__builtin_fmaf(val, whi.z, bhi.z));
        hv[7] = fast_tanh_s(__builtin_fmaf(val, whi.w, bhi.w));
        uint4 v;
        v.x = pack2(f2bf(hv[0]), f2bf(hv[1]));
        v.y = pack2(f2bf(hv[2]), f2bf(hv[3]));
        v.z = pack2(f2bf(hv[4]), f2bf(hv[5]));
        v.w = pack2(f2bf(hv[6]), f2bf(hv[7]));
        return v;
    };

    // ---- prologue (it=0): input first, then DMA (keeps tanh's wait at
    //      vmcnt(4) so the DMA queue is never drained early) ----
    const float val0 = x[(size_t)(m0 + arow) * FF + fi2];
    #pragma unroll
    for (int i = 0; i < 4; ++i) {
        const int seg = wave * 4 + i;      // 0..15
        gl_lds16(BtLane + (size_t)seg * 16 * KK, &Bs[seg * 512]);
    }
    wlo = reinterpret_cast<const float4*>(w1s)[fi2 * 2];
    whi = reinterpret_cast<const float4*>(w1s)[fi2 * 2 + 1];
    blo = reinterpret_cast<const float4*>(b1s)[fi2 * 2];
    bhi = reinterpret_cast<const float4*>(b1s)[fi2 * 2 + 1];
    pa = tanh_pack(val0);

    floatx4 acc[4][4];
    #pragma unroll
    for (int i = 0; i < 4; ++i)
        #pragma unroll
        for (int j = 0; j < 4; ++j)
            acc[i][j] = (floatx4){0.f, 0.f, 0.f, 0.f};

    for (int it = 0; it < 32; ++it) {
        const int buf = it & 1;
        const int itn = (it < 31) ? it + 1 : 31;   // clamp keeps vmem counts uniform
        const int brn = itn >> 4;
        const int fn  = ((itn & 15) << 2) + fi2;

        // 1) next input (1 vmem — issued BEFORE the DMAs)
        const float* __restrict__ inpn = brn ? tmv : x;
        const float nval = inpn[(size_t)(m0 + arow) * FF + fn];

        // 2) next B-tile DMA into buf^1 (4 vmem)
        {
            unsigned short* BsN = &Bs[(buf ^ 1) * (256 * 32)];
            const unsigned short* src = BtLane + (size_t)itn * 32;
            #pragma unroll
            for (int i = 0; i < 4; ++i) {
                const int seg = wave * 4 + i;
                gl_lds16(src + (size_t)seg * 16 * KK, BsN + seg * 512);
            }
        }

        // 3) current As store + next w/b LDS reads (all lgkm)
        *reinterpret_cast<uint4*>(&As[asoff]) = pa;
        const float4 nwlo = reinterpret_cast<const float4*>(w1s)[brn * 128 + fn * 2];
        const float4 nwhi = reinterpret_cast<const float4*>(w1s)[brn * 128 + fn * 2 + 1];
        const float4 nblo = reinterpret_cast<const float4*>(b1s)[brn * 128 + fn * 2];
        const float4 nbhi = reinterpret_cast<const float4*>(b1s)[brn * 128 + fn * 2 + 1];

        // barrier1: wait current DMA (6th-oldest) + all LDS ops; leave the
        // 5 just-issued vmem (input + 4 DMA) in flight across the barrier.
        asm volatile("s_waitcnt vmcnt(5) lgkmcnt(0)\n\ts_barrier" ::: "memory");

        // ---- MFMA phase on Bs[buf] + As ----
        {
            const unsigned short* BsC = &Bs[buf * (256 * 32)];
            bf16x8 af[4], bfr[4];
            #pragma unroll
            for (int mt = 0; mt < 4; ++mt)
                af[mt] = *reinterpret_cast<const bf16x8*>(&As[(mt * 16 + ml) * 32 + fco]);
            #pragma unroll
            for (int nt = 0; nt < 4; ++nt)
                bfr[nt] = *reinterpret_cast<const bf16x8*>(
                    &BsC[(wn * 64 + nt * 16 + ml) * 32 + fco]);
            #pragma unroll
            for (int mt = 0; mt < 4; ++mt)
                #pragma unroll
                for (int nt = 0; nt < 4; ++nt)
                    acc[mt][nt] = __builtin_amdgcn_mfma_f32_16x16x32_bf16(
                        af[mt], bfr[nt], acc[mt][nt], 0, 0, 0);

            // next-iter tanh: pure VALU (input wait = vmcnt(4): DMA stays out)
            wlo = nwlo; whi = nwhi; blo = nblo; bhi = nbhi;
            pa = tanh_pack(nval);
        }

        // barrier2: LDS-read drain only — NO vmcnt drain (the prefetch DMA
        // remains in flight into the next iteration).
        asm volatile("s_waitcnt lgkmcnt(0)\n\ts_barrier" ::: "memory");
    }

    // epilogue: nt innermost -> 4 consecutive 64B chunks per output row
    float bias[4];
    #pragma unroll
    for (int nt = 0; nt < 4; ++nt) {
        const int n = n0 + wn * 64 + nt * 16 + ml;
        bias[nt] = bx[n] + bt[n];
    }
    #pragma unroll
    for (int mt = 0; mt < 4; ++mt) {
        const int mb = m0 + mt * 16 + q * 4;
        #pragma unroll
        for (int r = 0; r < 4; ++r) {
            float* orow = out + (size_t)(mb + r) * PP + n0 + wn * 64 + ml;
            #pragma unroll
            for (int nt = 0; nt < 4; ++nt)
                orow[nt * 16] = acc[mt][nt][r] + bias[nt];
        }
    }
}

// ---------------------------------------------------------------------------
extern "C" void kernel_launch(void* const* d_in, const int* in_sizes, int n_in,
                              void* d_out, int out_size, void* d_ws, size_t ws_size,
                              hipStream_t stream)
{
    const float* x   = (const float*)d_in[0];
    const float* tmv = (const float*)d_in[1];
    const float* w1v = (const float*)d_in[2];
    const float* b1v = (const float*)d_in[3];
    const float* w2v = (const float*)d_in[4];
    const float* w1t = (const float*)d_in[5];
    const float* b1t = (const float*)d_in[6];
    const float* w2t = (const float*)d_in[7];
    const float* wx  = (const float*)d_in[8];
    const float* bx  = (const float*)d_in[9];
    const float* wt  = (const float*)d_in[10];
    const float* bt  = (const float*)d_in[11];
    float* out = (float*)d_out;

    // ws: [0,1MB) BmatT bf16 [512][1024]
    unsigned short* Bws = (unsigned short*)d_ws;

    combine_kernel<<<256, 256, 0, stream>>>(w2v, w2t, wx, wt, Bws);
    gemm_fused_kernel<<<dim3(MM / 64, PP / 256), 256, 0, stream>>>(
        x, tmv, w1v, b1v, w1t, b1t, Bws, bx, bt, out);
}